// Round 1
// baseline (909.774 us; speedup 1.0000x reference)
//
#include <hip/hip_runtime.h>

#define SEQ  2048
#define EMB  1024
#define NBAT 8
#define NROW (NBAT*SEQ)   // 16384

using u16 = unsigned short;
typedef float  f32x4  __attribute__((ext_vector_type(4)));
typedef __bf16 bf16x8 __attribute__((ext_vector_type(8)));
typedef u16    u16x8  __attribute__((ext_vector_type(8)));
typedef u16    u16x4  __attribute__((ext_vector_type(4)));

__device__ __forceinline__ u16 f2bf(float x) {
  unsigned u = __builtin_bit_cast(unsigned, x);
  return (u16)((u + 0x7fffu + ((u >> 16) & 1u)) >> 16);  // RNE, finite inputs
}
__device__ __forceinline__ float bf2f(u16 h) {
  return __builtin_bit_cast(float, ((unsigned)h) << 16);
}

__device__ __forceinline__ f32x4 mfma16(u16x8 a, u16x8 b, f32x4 c) {
  return __builtin_amdgcn_mfma_f32_16x16x32_bf16(
      __builtin_bit_cast(bf16x8, a), __builtin_bit_cast(bf16x8, b), c, 0, 0, 0);
}

// ---- LDS staging: 128x32 bf16 tiles; 16B-chunk XOR swizzle (chunk ^= row&3)
// gives <=2-way bank aliasing on ds_read_b128 fragment reads (free, m136). ----

template<bool LO>
__device__ __forceinline__ void stage_f32(const float* __restrict__ src, int ld,
                                          u16 (*__restrict__ lh)[32],
                                          u16 (*__restrict__ ll)[32], int t)
{
  const int row = t >> 1;
  const int cb  = (t & 1) * 16;
  const float* p = src + (size_t)row * ld + cb;
  f32x4 v[4];
  v[0] = *(const f32x4*)(p);
  v[1] = *(const f32x4*)(p + 4);
  v[2] = *(const f32x4*)(p + 8);
  v[3] = *(const f32x4*)(p + 12);
  u16x8 H[2], L[2];
#pragma unroll
  for (int j = 0; j < 16; ++j) {
    float x = v[j >> 2][j & 3];
    u16 h = f2bf(x);
    H[j >> 3][j & 7] = h;
    if (LO) L[j >> 3][j & 7] = f2bf(x - bf2f(h));
  }
  const int c0 = (t & 1) * 2, sw = row & 3;
  *(u16x8*)&lh[row][(c0 ^ sw) * 8]       = H[0];
  *(u16x8*)&lh[row][((c0 + 1) ^ sw) * 8] = H[1];
  if (LO) {
    *(u16x8*)&ll[row][(c0 ^ sw) * 8]       = L[0];
    *(u16x8*)&ll[row][((c0 + 1) ^ sw) * 8] = L[1];
  }
}

__device__ __forceinline__ void stage_bf16(const u16* __restrict__ src, int ld,
                                           u16 (*__restrict__ lh)[32], int t)
{
  const int row = t >> 1;
  const int cb  = (t & 1) * 16;
  const u16* p = src + (size_t)row * ld + cb;
  u16x8 u0 = *(const u16x8*)(p);
  u16x8 u1 = *(const u16x8*)(p + 8);
  const int c0 = (t & 1) * 2, sw = row & 3;
  *(u16x8*)&lh[row][(c0 ^ sw) * 8]       = u0;
  *(u16x8*)&lh[row][((c0 + 1) ^ sw) * 8] = u1;
}

__device__ __forceinline__ u16x8 ldfrag(const u16 (*__restrict__ lds)[32], int row, int kg)
{
  return *(const u16x8*)&lds[row][(kg ^ (row & 3)) * 8];
}

// One BK=32 step. A-frag: row = lane&15, k = (lane>>4)*8+j (m91/m92-verified NT layout).
// SPLIT: acc += Ah*Bh + Ah*Bl + Al*Bh  (drops Al*Bl ~ 2^-18).
template<bool SPLIT>
__device__ __forceinline__ void kstep(const u16 (*Ah)[32], const u16 (*Al)[32],
                                      const u16 (*Bh)[32], const u16 (*Bl)[32],
                                      int wr, int wc, int lane, f32x4 acc[4][4])
{
  const int r = lane & 15, kg = lane >> 4;
  u16x8 ah[4], al[4], bh[4], bl[4];
#pragma unroll
  for (int i = 0; i < 4; ++i) {
    ah[i] = ldfrag(Ah, wr * 64 + i * 16 + r, kg);
    bh[i] = ldfrag(Bh, wc * 64 + i * 16 + r, kg);
    if (SPLIT) {
      al[i] = ldfrag(Al, wr * 64 + i * 16 + r, kg);
      bl[i] = ldfrag(Bl, wc * 64 + i * 16 + r, kg);
    }
  }
#pragma unroll
  for (int i = 0; i < 4; ++i) {
#pragma unroll
    for (int j = 0; j < 4; ++j) {
      acc[i][j] = mfma16(ah[i], bh[j], acc[i][j]);
      if (SPLIT) {
        acc[i][j] = mfma16(ah[i], bl[j], acc[i][j]);
        acc[i][j] = mfma16(al[i], bh[j], acc[i][j]);
      }
    }
  }
}

// ---- 1) Split Wq/Wk/Wv into hi/lo bf16 once (re-staged 128x per GEMM otherwise)
__global__ __launch_bounds__(256) void prep_w_kernel(
    const float* __restrict__ Wq, const float* __restrict__ Wk, const float* __restrict__ Wv,
    u16* __restrict__ Wh, u16* __restrict__ Wl)
{
  const int m = blockIdx.y;
  const float* W = (m == 0) ? Wq : (m == 1) ? Wk : Wv;
  const size_t base = ((size_t)blockIdx.x * 256 + threadIdx.x) * 4;
  f32x4 v = *(const f32x4*)(W + base);
  u16x4 h, l;
#pragma unroll
  for (int j = 0; j < 4; ++j) {
    h[j] = f2bf(v[j]);
    l[j] = f2bf(v[j] - bf2f(h[j]));
  }
  *(u16x4*)&Wh[(size_t)m * EMB * EMB + base] = h;
  *(u16x4*)&Wl[(size_t)m * EMB * EMB + base] = l;
}

// ---- 2) Fused QKV projection: C = X * W^T + b, split-bf16 (3 MFMA/step).
// z = 0:Q (write hi/lo), 1:K (write hi/lo into out0 scratch), 2:V (write V^T bf16)
__global__ __launch_bounds__(256) void proj_kernel(
    const float* __restrict__ X,
    const u16* __restrict__ Wh, const u16* __restrict__ Wl,
    const float* __restrict__ bq, const float* __restrict__ bk, const float* __restrict__ bv,
    u16* __restrict__ Qh, u16* __restrict__ Ql,
    u16* __restrict__ Kh, u16* __restrict__ Kl,
    u16* __restrict__ VT)
{
  __shared__ alignas(16) u16 sAh[128][32];
  __shared__ alignas(16) u16 sAl[128][32];
  __shared__ alignas(16) u16 sBh[128][32];
  __shared__ alignas(16) u16 sBl[128][32];

  const int mat = blockIdx.z;
  const int n0  = blockIdx.x * 128;
  const int m0  = blockIdx.y * 128;
  const int t = threadIdx.x, lane = t & 63, wid = t >> 6;
  const int wr = wid >> 1, wc = wid & 1;

  const u16* Wmh = Wh + (size_t)mat * EMB * EMB;
  const u16* Wml = Wl + (size_t)mat * EMB * EMB;

  f32x4 acc[4][4];
#pragma unroll
  for (int i = 0; i < 4; ++i)
#pragma unroll
    for (int j = 0; j < 4; ++j)
#pragma unroll
      for (int q = 0; q < 4; ++q) acc[i][j][q] = 0.0f;

  for (int kt = 0; kt < EMB; kt += 32) {
    __syncthreads();
    stage_f32<true>(X + (size_t)m0 * EMB + kt, EMB, sAh, sAl, t);
    stage_bf16(Wmh + (size_t)n0 * EMB + kt, EMB, sBh, t);
    stage_bf16(Wml + (size_t)n0 * EMB + kt, EMB, sBl, t);
    __syncthreads();
    kstep<true>(sAh, sAl, sBh, sBl, wr, wc, lane, acc);
  }

  const float* bias = (mat == 0) ? bq : (mat == 1) ? bk : bv;
  const int r = lane & 15, kg = lane >> 4;
#pragma unroll
  for (int i = 0; i < 4; ++i) {
#pragma unroll
    for (int j = 0; j < 4; ++j) {
      const int c = n0 + wc * 64 + j * 16 + r;        // C/D: col = lane&15 (m89)
      const float bb = bias[c];
#pragma unroll
      for (int rg = 0; rg < 4; ++rg) {
        const int row = m0 + wr * 64 + i * 16 + kg * 4 + rg;  // row = (lane>>4)*4+reg
        const float val = acc[i][j][rg] + bb;
        if (mat == 0) {
          const u16 h = f2bf(val);
          Qh[(size_t)row * EMB + c] = h;
          Ql[(size_t)row * EMB + c] = f2bf(val - bf2f(h));
        } else if (mat == 1) {
          const u16 h = f2bf(val);
          Kh[(size_t)row * EMB + c] = h;
          Kl[(size_t)row * EMB + c] = f2bf(val - bf2f(h));
        } else {
          const int bi = row >> 11, s = row & (SEQ - 1);
          VT[((size_t)bi * EMB + c) * SEQ + s] = f2bf(val);   // V^T [b][d][s], plain bf16
        }
      }
    }
  }
}

// ---- 3) scores = g_q * g_k * (Q . K) / 32, split-bf16; raw scores -> attn region
__global__ __launch_bounds__(256) void scores_kernel(
    const u16* __restrict__ Qh, const u16* __restrict__ Ql,
    const u16* __restrict__ Kh, const u16* __restrict__ Kl,
    const float* __restrict__ gates, float* __restrict__ attn)
{
  __shared__ alignas(16) u16 sAh[128][32];
  __shared__ alignas(16) u16 sAl[128][32];
  __shared__ alignas(16) u16 sBh[128][32];
  __shared__ alignas(16) u16 sBl[128][32];

  const int b  = blockIdx.z;
  const int n0 = blockIdx.x * 128;   // key tile
  const int q0 = blockIdx.y * 128;   // query tile
  const int t = threadIdx.x, lane = t & 63, wid = t >> 6;
  const int wr = wid >> 1, wc = wid & 1;

  const size_t qbase = ((size_t)b * SEQ + q0) * EMB;
  const size_t kbase = ((size_t)b * SEQ + n0) * EMB;

  f32x4 acc[4][4];
#pragma unroll
  for (int i = 0; i < 4; ++i)
#pragma unroll
    for (int j = 0; j < 4; ++j)
#pragma unroll
      for (int q = 0; q < 4; ++q) acc[i][j][q] = 0.0f;

  for (int kt = 0; kt < EMB; kt += 32) {
    __syncthreads();
    stage_bf16(Qh + qbase + kt, EMB, sAh, t);
    stage_bf16(Ql + qbase + kt, EMB, sAl, t);
    stage_bf16(Kh + kbase + kt, EMB, sBh, t);
    stage_bf16(Kl + kbase + kt, EMB, sBl, t);
    __syncthreads();
    kstep<true>(sAh, sAl, sBh, sBl, wr, wc, lane, acc);
  }

  const float* gb = gates + (size_t)b * SEQ;
  float* Sb = attn + (size_t)b * SEQ * SEQ;
  const int r = lane & 15, kg = lane >> 4;
#pragma unroll
  for (int i = 0; i < 4; ++i) {
#pragma unroll
    for (int j = 0; j < 4; ++j) {
      const int col = n0 + wc * 64 + j * 16 + r;
      const float gk = gb[col] * 0.03125f;           // 1/sqrt(1024)
#pragma unroll
      for (int rg = 0; rg < 4; ++rg) {
        const int rowl = q0 + wr * 64 + i * 16 + kg * 4 + rg;
        Sb[(size_t)rowl * SEQ + col] = acc[i][j][rg] * gb[rowl] * gk;
      }
    }
  }
}

// ---- 4) in-place row softmax over 2048 cols; one block per row
__global__ __launch_bounds__(256) void softmax_kernel(float* __restrict__ attn)
{
  float* row = attn + (size_t)blockIdx.x * SEQ;
  const int t = threadIdx.x, lane = t & 63, wid = t >> 6;
  f32x4 v0 = *(const f32x4*)(row + t * 8);
  f32x4 v1 = *(const f32x4*)(row + t * 8 + 4);
  float m = fmaxf(fmaxf(fmaxf(v0[0], v0[1]), fmaxf(v0[2], v0[3])),
                  fmaxf(fmaxf(v1[0], v1[1]), fmaxf(v1[2], v1[3])));
#pragma unroll
  for (int off = 32; off >= 1; off >>= 1) m = fmaxf(m, __shfl_xor(m, off));
  __shared__ float red[4];
  if (lane == 0) red[wid] = m;
  __syncthreads();
  m = fmaxf(fmaxf(red[0], red[1]), fmaxf(red[2], red[3]));
  f32x4 e0, e1;
  float s = 0.f;
#pragma unroll
  for (int j = 0; j < 4; ++j) { e0[j] = expf(v0[j] - m); s += e0[j]; }
#pragma unroll
  for (int j = 0; j < 4; ++j) { e1[j] = expf(v1[j] - m); s += e1[j]; }
#pragma unroll
  for (int off = 32; off >= 1; off >>= 1) s += __shfl_xor(s, off);
  __syncthreads();
  if (lane == 0) red[wid] = s;
  __syncthreads();
  s = (red[0] + red[1]) + (red[2] + red[3]);
  const float inv = 1.0f / s;
#pragma unroll
  for (int j = 0; j < 4; ++j) { e0[j] *= inv; e1[j] *= inv; }
  *(f32x4*)(row + t * 8)     = e0;
  *(f32x4*)(row + t * 8 + 4) = e1;
}

// ---- 5) out = P * V, plain bf16 (errors shrunk by convex weights)
__global__ __launch_bounds__(256) void pv_kernel(
    const float* __restrict__ attn, const u16* __restrict__ VT, float* __restrict__ out)
{
  __shared__ alignas(16) u16 sAh[128][32];
  __shared__ alignas(16) u16 sBh[128][32];

  const int b  = blockIdx.z;
  const int d0 = blockIdx.x * 128;
  const int q0 = blockIdx.y * 128;
  const int t = threadIdx.x, lane = t & 63, wid = t >> 6;
  const int wr = wid >> 1, wc = wid & 1;

  const float* Pb = attn + (size_t)b * SEQ * SEQ + (size_t)q0 * SEQ;
  const u16*   Vb = VT   + (size_t)b * EMB * SEQ + (size_t)d0 * SEQ;

  f32x4 acc[4][4];
#pragma unroll
  for (int i = 0; i < 4; ++i)
#pragma unroll
    for (int j = 0; j < 4; ++j)
#pragma unroll
      for (int q = 0; q < 4; ++q) acc[i][j][q] = 0.0f;

  for (int kt = 0; kt < SEQ; kt += 32) {
    __syncthreads();
    stage_f32<false>(Pb + kt, SEQ, sAh, sAh, t);
    stage_bf16(Vb + kt, SEQ, sBh, t);
    __syncthreads();
    kstep<false>(sAh, sAh, sBh, sBh, wr, wc, lane, acc);
  }

  const int r = lane & 15, kg = lane >> 4;
#pragma unroll
  for (int i = 0; i < 4; ++i) {
#pragma unroll
    for (int j = 0; j < 4; ++j) {
      const int col = d0 + wc * 64 + j * 16 + r;
#pragma unroll
      for (int rg = 0; rg < 4; ++rg) {
        const int rowl = q0 + wr * 64 + i * 16 + kg * 4 + rg;
        out[((size_t)b * SEQ + rowl) * EMB + col] = acc[i][j][rg];
      }
    }
  }
}

extern "C" void kernel_launch(void* const* d_in, const int* in_sizes, int n_in,
                              void* d_out, int out_size, void* d_ws, size_t ws_size,
                              hipStream_t stream) {
  const float* X  = (const float*)d_in[0];
  const float* g  = (const float*)d_in[1];
  const float* Wq = (const float*)d_in[2];
  const float* bq = (const float*)d_in[3];
  const float* Wk = (const float*)d_in[4];
  const float* bk = (const float*)d_in[5];
  const float* Wv = (const float*)d_in[6];
  const float* bv = (const float*)d_in[7];

  float* out0 = (float*)d_out;                         // [8,2048,1024] final PV output
  float* attn = out0 + (size_t)NROW * EMB;             // [8,2048,2048] attn weights

  // workspace layout (bytes): Qh 32M | Ql 32M | VT 32M | Wh 6M | Wl 6M = 108 MB
  const size_t need = (size_t)NROW * EMB * 2 * 2       // Qh,Ql
                    + (size_t)NBAT * EMB * SEQ * 2     // VT
                    + (size_t)3 * EMB * EMB * 2 * 2;   // Wh,Wl
  if (ws_size < need) return;                          // would mis-validate loudly
  u16* Qh = (u16*)d_ws;
  u16* Ql = Qh + (size_t)NROW * EMB;
  u16* VT = Ql + (size_t)NROW * EMB;
  u16* Wh = VT + (size_t)NBAT * EMB * SEQ;
  u16* Wl = Wh + (size_t)3 * EMB * EMB;
  // K hi/lo live in out0 (dead until pv_kernel overwrites it)
  u16* Kh = (u16*)out0;
  u16* Kl = Kh + (size_t)NROW * EMB;

  prep_w_kernel <<<dim3(EMB * EMB / (256 * 4), 3), 256, 0, stream>>>(Wq, Wk, Wv, Wh, Wl);
  proj_kernel   <<<dim3(EMB / 128, NROW / 128, 3), 256, 0, stream>>>(
      X, Wh, Wl, bq, bk, bv, Qh, Ql, Kh, Kl, VT);
  scores_kernel <<<dim3(SEQ / 128, SEQ / 128, NBAT), 256, 0, stream>>>(
      Qh, Ql, Kh, Kl, g, attn);
  softmax_kernel<<<dim3(NROW), 256, 0, stream>>>(attn);
  pv_kernel     <<<dim3(EMB / 128, SEQ / 128, NBAT), 256, 0, stream>>>(attn, VT, out0);
}

// Round 2
// 464.273 us; speedup vs baseline: 1.9596x; 1.9596x over previous
//
#include <hip/hip_runtime.h>

#define SEQ  2048
#define EMB  1024
#define NBAT 8
#define NROW (NBAT*SEQ)   // 16384

using u16 = unsigned short;
typedef float  f32x4  __attribute__((ext_vector_type(4)));
typedef __bf16 bf16x8 __attribute__((ext_vector_type(8)));
typedef u16    u16x8  __attribute__((ext_vector_type(8)));
typedef u16    u16x4  __attribute__((ext_vector_type(4)));

__device__ __forceinline__ u16 f2bf(float x) {
  unsigned u = __builtin_bit_cast(unsigned, x);
  return (u16)((u + 0x7fffu + ((u >> 16) & 1u)) >> 16);  // RNE, finite inputs
}

__device__ __forceinline__ f32x4 mfma16(u16x8 a, u16x8 b, f32x4 c) {
  return __builtin_amdgcn_mfma_f32_16x16x32_bf16(
      __builtin_bit_cast(bf16x8, a), __builtin_bit_cast(bf16x8, b), c, 0, 0, 0);
}

// async global->LDS, 16B per lane (ladder step 3: +67%). LDS dest must be
// wave-uniform base; HW adds lane*16. LDS layout is LINEAR (required; T2
// swizzle is null at 2-phase anyway per regime gate).
__device__ __forceinline__ void async_cp16(const u16* g, u16* l) {
  __builtin_amdgcn_global_load_lds(
      (const __attribute__((address_space(1))) void*)(g),
      (__attribute__((address_space(3))) void*)(l), 16, 0, 0);
}

// Stage a 128x32 bf16 tile (row-major global, ld elements) into linear LDS[128][32].
// Wave wid covers rows [wid*32, wid*32+32): 2 instrs x (64 lanes x 16B = 16 rows).
__device__ __forceinline__ void gload_tile(const u16* __restrict__ g, int ld,
                                           u16* __restrict__ lds, int wid, int lane)
{
#pragma unroll
  for (int l = 0; l < 2; ++l) {
    const int r0 = wid * 32 + l * 16;
    const u16* src = g + (size_t)(r0 + (lane >> 2)) * ld + (lane & 3) * 8;
    async_cp16(src, lds + r0 * 32);   // uniform base per wave
  }
}

// Reg-staged f32->bf16 tile (for PV's P operand; conversion forces the reg path).
__device__ __forceinline__ void stage_f32lin(const float* __restrict__ src, int ld,
                                             u16* __restrict__ lds, int t)
{
  const int row = t >> 1;
  const int cb  = (t & 1) * 16;
  const float* p = src + (size_t)row * ld + cb;
  f32x4 v0 = *(const f32x4*)(p);
  f32x4 v1 = *(const f32x4*)(p + 4);
  f32x4 v2 = *(const f32x4*)(p + 8);
  f32x4 v3 = *(const f32x4*)(p + 12);
  u16x8 H0, H1;
#pragma unroll
  for (int j = 0; j < 4; ++j) { H0[j] = f2bf(v0[j]); H0[j + 4] = f2bf(v1[j]); }
#pragma unroll
  for (int j = 0; j < 4; ++j) { H1[j] = f2bf(v2[j]); H1[j + 4] = f2bf(v3[j]); }
  *(u16x8*)&lds[row * 32 + cb]     = H0;
  *(u16x8*)&lds[row * 32 + cb + 8] = H1;
}

// One BK=32 step: 8 ds_read_b128 + 16 MFMA (m97 hot-loop shape).
// A-frag: row = lane&15, k = (lane>>4)*8+j (m91/m92 NT layout).
__device__ __forceinline__ void kstep(const u16* __restrict__ sA, const u16* __restrict__ sB,
                                      int wr, int wc, int lane, f32x4 acc[4][4])
{
  const int r = lane & 15, kg = lane >> 4;
  u16x8 a[4], b[4];
#pragma unroll
  for (int i = 0; i < 4; ++i) {
    a[i] = *(const u16x8*)&sA[(wr * 64 + i * 16 + r) * 32 + kg * 8];
    b[i] = *(const u16x8*)&sB[(wc * 64 + i * 16 + r) * 32 + kg * 8];
  }
#pragma unroll
  for (int i = 0; i < 4; ++i)
#pragma unroll
    for (int j = 0; j < 4; ++j)
      acc[i][j] = mfma16(a[i], b[j], acc[i][j]);
}

// XCD-chunked swizzle (m157; all grids here are %8==0 so it's bijective).
__device__ __forceinline__ int xcd_swz(int bid, int nwg) {
  return (bid & 7) * (nwg >> 3) + (bid >> 3);
}

// ---- 1) One-shot bf16 conversion of X and Wq/Wk/Wv.
__global__ __launch_bounds__(256) void prep_kernel(
    const float* __restrict__ X,
    const float* __restrict__ Wq, const float* __restrict__ Wk, const float* __restrict__ Wv,
    u16* __restrict__ Xb, u16* __restrict__ Wb)
{
  const size_t i = ((size_t)blockIdx.x * 256 + threadIdx.x) * 4;
  const size_t nx = (size_t)NROW * EMB;
  f32x4 v;
  u16* dst;
  if (i < nx) {
    v = *(const f32x4*)(X + i);
    dst = Xb + i;
  } else {
    const size_t j = i - nx;
    const int m = (int)(j / ((size_t)EMB * EMB));
    const size_t o = j - (size_t)m * EMB * EMB;
    const float* W = (m == 0) ? Wq : (m == 1) ? Wk : Wv;
    v = *(const f32x4*)(W + o);
    dst = Wb + j;
  }
  u16x4 h;
#pragma unroll
  for (int j = 0; j < 4; ++j) h[j] = f2bf(v[j]);
  *(u16x4*)dst = h;
}

// ---- 2) Fused QKV projection: C = Xb * Wb^T + b  (plain bf16, 1 MFMA/step)
// mat 0 -> Qb, 1 -> Kb (both in out0 scratch), 2 -> V^T bf16
__global__ __launch_bounds__(256) void proj_kernel(
    const u16* __restrict__ Xb, const u16* __restrict__ Wb,
    const float* __restrict__ bq, const float* __restrict__ bk, const float* __restrict__ bv,
    u16* __restrict__ Qb, u16* __restrict__ Kb, u16* __restrict__ VT)
{
  __shared__ alignas(16) u16 sA[128 * 32];
  __shared__ alignas(16) u16 sB[128 * 32];

  const int nwg = (EMB / 128) * (NROW / 128) * 3;       // 3072
  int wg = xcd_swz(blockIdx.x, nwg);
  const int n0 = (wg & 7) * 128;        wg >>= 3;       // 8 n-blocks (fastest: share X strip)
  const int m0 = (wg & 127) * 128;      wg >>= 7;       // 128 m-blocks
  const int mat = wg;                                   // 3 matrices

  const int t = threadIdx.x, lane = t & 63, wid = t >> 6;
  const int wr = wid >> 1, wc = wid & 1;

  const u16* A = Xb + (size_t)m0 * EMB;
  const u16* B = Wb + (size_t)mat * EMB * EMB + (size_t)n0 * EMB;

  f32x4 acc[4][4];
#pragma unroll
  for (int i = 0; i < 4; ++i)
#pragma unroll
    for (int j = 0; j < 4; ++j)
#pragma unroll
      for (int q = 0; q < 4; ++q) acc[i][j][q] = 0.0f;

  for (int kt = 0; kt < EMB; kt += 32) {
    __syncthreads();
    gload_tile(A + kt, EMB, sA, wid, lane);
    gload_tile(B + kt, EMB, sB, wid, lane);
    __syncthreads();                    // compiler drains vmcnt(0) here
    kstep(sA, sB, wr, wc, lane, acc);
  }

  const float* bias = (mat == 0) ? bq : (mat == 1) ? bk : bv;
  const int r = lane & 15, kg = lane >> 4;
#pragma unroll
  for (int i = 0; i < 4; ++i) {
#pragma unroll
    for (int j = 0; j < 4; ++j) {
      const int c = n0 + wc * 64 + j * 16 + r;                  // col = lane&15 (m89)
      const float bb = bias[c];
#pragma unroll
      for (int rg = 0; rg < 4; ++rg) {
        const int row = m0 + wr * 64 + i * 16 + kg * 4 + rg;    // row = (lane>>4)*4+reg
        const u16 h = f2bf(acc[i][j][rg] + bb);
        if (mat == 0) {
          Qb[(size_t)row * EMB + c] = h;
        } else if (mat == 1) {
          Kb[(size_t)row * EMB + c] = h;
        } else {
          const int bi = row >> 11, s = row & (SEQ - 1);
          VT[((size_t)bi * EMB + c) * SEQ + s] = h;             // V^T [b][d][s]
        }
      }
    }
  }
}

// ---- 3) scores = g_q * g_k * (Q . K) / 32 -> raw scores into attn region
__global__ __launch_bounds__(256) void scores_kernel(
    const u16* __restrict__ Qb, const u16* __restrict__ Kb,
    const float* __restrict__ gates, float* __restrict__ attn)
{
  __shared__ alignas(16) u16 sA[128 * 32];
  __shared__ alignas(16) u16 sB[128 * 32];

  const int nwg = 16 * 16 * NBAT;                       // 2048; chunk = 1 batch/XCD
  int wg = xcd_swz(blockIdx.x, nwg);
  const int n0 = (wg & 15) * 128;       wg >>= 4;       // key tile (fastest)
  const int q0 = (wg & 15) * 128;       wg >>= 4;       // query tile
  const int b  = wg;

  const int t = threadIdx.x, lane = t & 63, wid = t >> 6;
  const int wr = wid >> 1, wc = wid & 1;

  const u16* A = Qb + ((size_t)b * SEQ + q0) * EMB;
  const u16* B = Kb + ((size_t)b * SEQ + n0) * EMB;

  f32x4 acc[4][4];
#pragma unroll
  for (int i = 0; i < 4; ++i)
#pragma unroll
    for (int j = 0; j < 4; ++j)
#pragma unroll
      for (int q = 0; q < 4; ++q) acc[i][j][q] = 0.0f;

  for (int kt = 0; kt < EMB; kt += 32) {
    __syncthreads();
    gload_tile(A + kt, EMB, sA, wid, lane);
    gload_tile(B + kt, EMB, sB, wid, lane);
    __syncthreads();
    kstep(sA, sB, wr, wc, lane, acc);
  }

  const float* gb = gates + (size_t)b * SEQ;
  float* Sb = attn + (size_t)b * SEQ * SEQ;
  const int r = lane & 15, kg = lane >> 4;
#pragma unroll
  for (int i = 0; i < 4; ++i) {
#pragma unroll
    for (int j = 0; j < 4; ++j) {
      const int col = n0 + wc * 64 + j * 16 + r;
      const float gk = gb[col] * 0.03125f;              // 1/sqrt(1024)
#pragma unroll
      for (int rg = 0; rg < 4; ++rg) {
        const int rowl = q0 + wr * 64 + i * 16 + kg * 4 + rg;
        Sb[(size_t)rowl * SEQ + col] = acc[i][j][rg] * gb[rowl] * gk;
      }
    }
  }
}

// ---- 4) in-place row softmax over 2048 cols; one block per row
__global__ __launch_bounds__(256) void softmax_kernel(float* __restrict__ attn)
{
  float* row = attn + (size_t)blockIdx.x * SEQ;
  const int t = threadIdx.x, lane = t & 63, wid = t >> 6;
  f32x4 v0 = *(const f32x4*)(row + t * 8);
  f32x4 v1 = *(const f32x4*)(row + t * 8 + 4);
  float m = fmaxf(fmaxf(fmaxf(v0[0], v0[1]), fmaxf(v0[2], v0[3])),
                  fmaxf(fmaxf(v1[0], v1[1]), fmaxf(v1[2], v1[3])));
#pragma unroll
  for (int off = 32; off >= 1; off >>= 1) m = fmaxf(m, __shfl_xor(m, off));
  __shared__ float red[4];
  if (lane == 0) red[wid] = m;
  __syncthreads();
  m = fmaxf(fmaxf(red[0], red[1]), fmaxf(red[2], red[3]));
  f32x4 e0, e1;
  float s = 0.f;
#pragma unroll
  for (int j = 0; j < 4; ++j) { e0[j] = expf(v0[j] - m); s += e0[j]; }
#pragma unroll
  for (int j = 0; j < 4; ++j) { e1[j] = expf(v1[j] - m); s += e1[j]; }
#pragma unroll
  for (int off = 32; off >= 1; off >>= 1) s += __shfl_xor(s, off);
  __syncthreads();
  if (lane == 0) red[wid] = s;
  __syncthreads();
  s = (red[0] + red[1]) + (red[2] + red[3]);
  const float inv = 1.0f / s;
#pragma unroll
  for (int j = 0; j < 4; ++j) { e0[j] *= inv; e1[j] *= inv; }
  *(f32x4*)(row + t * 8)     = e0;
  *(f32x4*)(row + t * 8 + 4) = e1;
}

// ---- 5) out = P * V (P reg-staged f32->bf16; V^T via global_load_lds)
__global__ __launch_bounds__(256) void pv_kernel(
    const float* __restrict__ attn, const u16* __restrict__ VT, float* __restrict__ out)
{
  __shared__ alignas(16) u16 sA[128 * 32];
  __shared__ alignas(16) u16 sB[128 * 32];

  const int nwg = 8 * 16 * NBAT;                        // 1024
  int wg = xcd_swz(blockIdx.x, nwg);
  const int d0 = (wg & 7) * 128;        wg >>= 3;       // d tile (fastest: share P strip)
  const int q0 = (wg & 15) * 128;       wg >>= 4;       // q tile
  const int b  = wg;

  const int t = threadIdx.x, lane = t & 63, wid = t >> 6;
  const int wr = wid >> 1, wc = wid & 1;

  const float* Pb = attn + (size_t)b * SEQ * SEQ + (size_t)q0 * SEQ;
  const u16*   Vb = VT   + (size_t)b * EMB * SEQ + (size_t)d0 * SEQ;

  f32x4 acc[4][4];
#pragma unroll
  for (int i = 0; i < 4; ++i)
#pragma unroll
    for (int j = 0; j < 4; ++j)
#pragma unroll
      for (int q = 0; q < 4; ++q) acc[i][j][q] = 0.0f;

  for (int kt = 0; kt < SEQ; kt += 32) {
    __syncthreads();
    stage_f32lin(Pb + kt, SEQ, sA, t);
    gload_tile(Vb + kt, SEQ, sB, wid, lane);
    __syncthreads();
    kstep(sA, sB, wr, wc, lane, acc);
  }

  const int r = lane & 15, kg = lane >> 4;
#pragma unroll
  for (int i = 0; i < 4; ++i) {
#pragma unroll
    for (int j = 0; j < 4; ++j) {
      const int col = d0 + wc * 64 + j * 16 + r;
#pragma unroll
      for (int rg = 0; rg < 4; ++rg) {
        const int rowl = q0 + wr * 64 + i * 16 + kg * 4 + rg;
        out[((size_t)b * SEQ + rowl) * EMB + col] = acc[i][j][rg];
      }
    }
  }
}

extern "C" void kernel_launch(void* const* d_in, const int* in_sizes, int n_in,
                              void* d_out, int out_size, void* d_ws, size_t ws_size,
                              hipStream_t stream) {
  const float* X  = (const float*)d_in[0];
  const float* g  = (const float*)d_in[1];
  const float* Wq = (const float*)d_in[2];
  const float* bq = (const float*)d_in[3];
  const float* Wk = (const float*)d_in[4];
  const float* bk = (const float*)d_in[5];
  const float* Wv = (const float*)d_in[6];
  const float* bv = (const float*)d_in[7];

  float* out0 = (float*)d_out;                          // [8,2048,1024] final PV output
  float* attn = out0 + (size_t)NROW * EMB;              // [8,2048,2048] attn weights

  // ws: Xb 33.5M | VT 33.5M | Wb 6.3M  = ~73.4 MB (known-safe <= 108 MB)
  const size_t need = ((size_t)NROW * EMB + (size_t)NBAT * EMB * SEQ
                       + (size_t)3 * EMB * EMB) * 2;
  if (ws_size < need) return;
  u16* Xb = (u16*)d_ws;
  u16* VT = Xb + (size_t)NROW * EMB;
  u16* Wb = VT + (size_t)NBAT * EMB * SEQ;
  // Qb/Kb live in out0 (dead until pv_kernel fully overwrites it): 67.1 MB exactly
  u16* Qb = (u16*)out0;
  u16* Kb = Qb + (size_t)NROW * EMB;

  const int prep_blocks = (int)(((size_t)NROW * EMB + (size_t)3 * EMB * EMB) / 1024);
  prep_kernel   <<<dim3(prep_blocks), 256, 0, stream>>>(X, Wq, Wk, Wv, Xb, Wb);
  proj_kernel   <<<dim3((EMB / 128) * (NROW / 128) * 3), 256, 0, stream>>>(
      Xb, Wb, bq, bk, bv, Qb, Kb, VT);
  scores_kernel <<<dim3(16 * 16 * NBAT), 256, 0, stream>>>(Qb, Kb, g, attn);
  softmax_kernel<<<dim3(NROW), 256, 0, stream>>>(attn);
  pv_kernel     <<<dim3(8 * 16 * NBAT), 256, 0, stream>>>(attn, VT, out0);
}